// Round 6
// baseline (76.515 us; speedup 1.0000x reference)
//
#include <hip/hip_runtime.h>

// StructuredMAPLoss: B=1024 rows, C=128 classes.
// out[0] = loss (mean over classes), out[1 + i*C + c] = ranking[i][c].
// Kernel A: coalesced transpose+classify -> keysT[c][i] (u64) in d_ws.
//   key = (inv<<44) | (kw<<12) | (i<<2) | f   (sort order: inv, kw, idx; f inert)
// Kernel B: one block (512 thr x 2 elem) per class; loads only keysT (16B/lane
// coalesced). Bitonic sort (j==1 in-reg, j<=64 shfl, j>=128 dbuf-LDS),
// r-histogram for pairwise counts.

constexpr int Bn = 1024;
constexpr int Cn = 128;
constexpr int TPB = 512;
constexpr int E = 2;
constexpr int NBINS = 2048;
constexpr int ROFF = 3072;   // bin = (r + ROFF) >> 1 ; valid r in [-3071, 1023]

__device__ __forceinline__ unsigned long long pk3(int ff) {
    return (ff != 0 ? 1ull : 0ull) + (ff == 2 ? (1ull << 21) : 0ull) + (ff == 1 ? (1ull << 42) : 0ull);
}

// ---------------- Kernel A: transpose + classify + key build ----------------
__global__ __launch_bounds__(256) void build_keys_kernel(
    const float* __restrict__ x,
    const int* __restrict__ tgt,
    const void* __restrict__ maskraw,
    unsigned long long* __restrict__ keysT)
{
    __shared__ unsigned long long tile[32][33];
    __shared__ int smode;

    if (threadIdx.x == 0) {
        const int*   wi = (const int*)maskraw;
        const float* wf = (const float*)maskraw;
        bool okInt = true, okF = true;
        for (int k = 0; k < 32; ++k) {
            int v = wi[k];
            if (v != 0 && v != 1) okInt = false;
            float fv = wf[k];
            if (fv != 0.0f && fv != 1.0f) okF = false;
        }
        smode = okInt ? 0 : (okF ? 1 : 2);
    }
    __syncthreads();
    const int mode = smode;

    const int tb_i = blockIdx.x & 31;    // 32 i-tiles
    const int tb_c = blockIdx.x >> 5;    // 4  c-tiles
    const int tc = threadIdx.x & 31;
    const int tr = threadIdx.x >> 5;     // 0..7

    #pragma unroll
    for (int q = 0; q < 4; ++q) {
        const int i_loc = tr + q * 8;
        const int i = tb_i * 32 + i_loc;
        const int c = tb_c * 32 + tc;
        const int g = i * Cn + c;
        float xv = x[g];
        int t = tgt[g];
        bool m;
        if (mode == 0)      m = ((const int*)maskraw)[g] != 0;
        else if (mode == 1) m = ((const float*)maskraw)[g] != 0.0f;
        else                m = ((const unsigned char*)maskraw)[g] != 0;
        int f = m ? ((t == 1) ? 1 : ((t == 0) ? 2 : 3)) : 0;

        unsigned int bits = __float_as_uint(xv);
        unsigned int masc = bits ^ ((bits >> 31) ? 0xFFFFFFFFu : 0x80000000u);
        unsigned int kw = ~masc;                          // descending-x sorts first
        unsigned long long inv = (f == 0) ? 1ull : 0ull;
        tile[i_loc][tc] = (inv << 44) | ((unsigned long long)kw << 12)
                        | ((unsigned long long)i << 2) | (unsigned long long)f;
    }
    __syncthreads();
    #pragma unroll
    for (int q = 0; q < 4; ++q) {
        const int c_loc = tr + q * 8;
        const int i_loc = tc;
        keysT[(tb_c * 32 + c_loc) * Bn + tb_i * 32 + i_loc] = tile[i_loc][c_loc];
    }
}

// ---------------- Kernel B: per-class loss ----------------
__global__ __launch_bounds__(TPB) void map_loss_kernel(
    const unsigned long long* __restrict__ keysT,
    float* __restrict__ out)
{
    __shared__ unsigned char fl[Bn];                 // 1 KB
    __shared__ unsigned long long kbuf[2][Bn];       // 16 KB (double buffer)
    __shared__ unsigned int hist[NBINS];             // 8 KB
    __shared__ unsigned long long wtot[8];
    __shared__ unsigned int hwt[8];
    __shared__ int iwt[8];
    __shared__ float red[5][8];

    const int c    = blockIdx.x;
    const int tid  = threadIdx.x;
    const int lane = tid & 63;
    const int wid  = tid >> 6;

    // ---- load 2 keys / thread (16B coalesced); unpack f, x ----
    unsigned long long kr[E];
    {
        const unsigned long long* p = keysT + c * Bn + tid * E;
        kr[0] = p[0];
        kr[1] = p[1];
    }
    float xv[E]; int f[E];
    #pragma unroll
    for (int e = 0; e < E; ++e) {
        f[e] = (int)(kr[e] & 3ull);
        unsigned int kw = (unsigned int)(kr[e] >> 12);
        unsigned int masc = ~kw;
        unsigned int bits = (masc & 0x80000000u) ? (masc ^ 0x80000000u) : ~masc;
        xv[e] = __float_as_uint(bits), xv[e] = __uint_as_float(bits);
        fl[tid * E + e] = (unsigned char)f[e];
    }
    #pragma unroll
    for (int q = 0; q < NBINS / TPB; ++q) hist[tid * (NBINS / TPB) + q] = 0u;

    // ---- packed (valid,neg,pos) prefix scan over element order ----
    unsigned long long local = pk3(f[0]) + pk3(f[1]);
    unsigned long long v = local;
    #pragma unroll
    for (int off = 1; off < 64; off <<= 1) {
        unsigned long long o = __shfl_up(v, off);
        if (lane >= off) v += o;
    }
    if (lane == 63) wtot[wid] = v;
    __syncthreads();                                 // fences fl + hist zero + wtot
    unsigned long long wpre = 0, tot = 0;
    #pragma unroll
    for (int w = 0; w < 8; ++w) {
        unsigned long long t = wtot[w];
        if (w < wid) wpre += t;
        tot += t;
    }
    unsigned long long run = wpre + v - local;       // exclusive prefix at i = tid*E

    const int M = (int)(tot & 0x1FFFFF);
    const int N = (int)((tot >> 21) & 0x1FFFFF);
    const int P = (int)((tot >> 42) & 0x1FFFFF);
    const bool active = (P > 0) && (N > 0);

    // ---- r closed form, ranking write, histogram atomics ----
    int r[E];
    #pragma unroll
    for (int e = 0; e < E; ++e) {
        const int i = tid * E + e;
        const int vb = (int)(run & 0x1FFFFF);
        const int nb = (int)((run >> 21) & 0x1FFFFF);
        const int pb = (int)((run >> 42) & 0x1FFFFF);
        const int mfi = (f[e] != 0) ? 1 : 0;
        const int bse = M - mfi - 2 * vb;
        r[e] = (f[e] == 1) ? bse + 2 * nb
             : ((f[e] == 2) ? bse + 2 * pb - 2 * P : bse);
        run += pk3(f[e]);

        out[1 + i * Cn + c] = (active && f[e] != 0) ? (float)r[e] : 0.0f;

        if (f[e] == 1)      atomicAdd(&hist[(r[e] + ROFF) >> 1], 1u << 16);
        else if (f[e] == 2) atomicAdd(&hist[(r[e] + ROFF) >> 1], 1u);
    }

    // ---- bitonic sort (ascending): j==1 in-reg, j=2..64 shfl, j>=128 LDS ----
    int lb = 0;
    #pragma unroll
    for (int k = 2; k <= Bn; k <<= 1) {
        #pragma unroll
        for (int j = k >> 1; j > 0; j >>= 1) {
            if (j >= 128) {
                kbuf[lb][tid * E]     = kr[0];
                kbuf[lb][tid * E + 1] = kr[1];
                __syncthreads();                     // 6 of these total
                const int ptid = tid ^ (j >> 1);
                #pragma unroll
                for (int e = 0; e < E; ++e) {
                    unsigned long long o = kbuf[lb][ptid * E + e];
                    const int i = tid * E + e;
                    bool keepmin = ((i & k) == 0) == ((i & j) == 0);
                    kr[e] = ((kr[e] < o) == keepmin) ? kr[e] : o;
                }
                lb ^= 1;                             // WAR safe: next write to this
            } else if (j >= E) {                     //   buffer is >=2 barriers away
                const int jl = j >> 1;               // lane distance 1..32
                #pragma unroll
                for (int e = 0; e < E; ++e) {
                    unsigned long long o = __shfl_xor(kr[e], jl);
                    const int i = tid * E + e;
                    bool keepmin = ((i & k) == 0) == ((i & j) == 0);
                    kr[e] = ((kr[e] < o) == keepmin) ? kr[e] : o;
                }
            } else {                                 // j == 1: within thread
                const int i0 = tid * E;
                bool up = ((i0 & k) == 0);
                unsigned long long a = kr[0], b = kr[1];
                bool sw = ((a > b) == up);
                kr[0] = sw ? b : a;
                kr[1] = sw ? a : b;
            }
        }
    }
    // kr[e] = key at sorted position i = tid*E+e (valids desc-x first, invalids last)

    // ---- histogram inclusive scan (4 bins/thread) + AP pos-indicator scan ----
    unsigned int h[NBINS / TPB]; unsigned int hl = 0;
    #pragma unroll
    for (int q = 0; q < NBINS / TPB; ++q) { h[q] = hist[tid * (NBINS / TPB) + q]; hl += h[q]; }
    unsigned int hv = hl;
    #pragma unroll
    for (int off = 1; off < 64; off <<= 1) {
        unsigned int o = __shfl_up(hv, off);
        if (lane >= off) hv += o;
    }
    if (lane == 63) hwt[wid] = hv;

    int ps[E]; int pl = 0;
    #pragma unroll
    for (int e = 0; e < E; ++e) { ps[e] = (fl[(kr[e] >> 2) & 0x3FF] == 1) ? 1 : 0; pl += ps[e]; }
    int pv = pl;
    #pragma unroll
    for (int off = 1; off < 64; off <<= 1) {
        int o = __shfl_up(pv, off);
        if (lane >= off) pv += o;
    }
    if (lane == 63) iwt[wid] = pv;
    __syncthreads();                                 // A: hwt + iwt ready

    unsigned int hpre = 0; int ppre = 0;
    #pragma unroll
    for (int w = 0; w < 8; ++w) {
        if (w < wid) { hpre += hwt[w]; ppre += iwt[w]; }
    }
    unsigned int hrun = hpre + hv - hl;
    #pragma unroll
    for (int q = 0; q < NBINS / TPB; ++q) { hrun += h[q]; hist[tid * (NBINS / TPB) + q] = hrun; }

    float S_ap = 0.0f;
    int prun = ppre + pv - pl;
    #pragma unroll
    for (int e = 0; e < E; ++e) {
        prun += ps[e];
        if (ps[e]) S_ap += (float)prun / (float)(tid * E + e + 1);
    }
    __syncthreads();                                 // B: inclusive hist visible

    // ---- per-element pairwise terms via histogram lookup ----
    float S_t1 = 0.0f, S_t2 = 0.0f, S_px = 0.0f, S_nx = 0.0f;
    #pragma unroll
    for (int e = 0; e < E; ++e) {
        if (f[e] == 1) {
            int rb = (r[e] + ROFF) >> 1;             // >= 1024, rb-1 safe
            int cnt = (int)(hist[rb - 1] & 0xFFFFu); // negs with r' < r
            S_t1 += xv[e] * (2.0f * (float)cnt - (float)N);
            S_px += xv[e];
        } else if (f[e] == 2) {
            int rb = (r[e] + ROFF) >> 1;
            int cnt = P - (int)(hist[rb] >> 16);     // pos with r' > r
            S_t2 += xv[e] * (2.0f * (float)cnt - (float)P);
            S_nx += xv[e];
        }
    }

    // ---- block reduction of 5 partial sums ----
    #pragma unroll
    for (int off = 32; off > 0; off >>= 1) {
        S_ap += __shfl_down(S_ap, off);
        S_t1 += __shfl_down(S_t1, off);
        S_t2 += __shfl_down(S_t2, off);
        S_px += __shfl_down(S_px, off);
        S_nx += __shfl_down(S_nx, off);
    }
    if (lane == 0) {
        red[0][wid] = S_ap; red[1][wid] = S_t1; red[2][wid] = S_t2;
        red[3][wid] = S_px; red[4][wid] = S_nx;
    }
    __syncthreads();
    if (tid == 0) {
        float apS = 0.f, t1 = 0.f, t2 = 0.f, px = 0.f, nx = 0.f;
        #pragma unroll
        for (int w = 0; w < 8; ++w) {
            apS += red[0][w]; t1 += red[1][w]; t2 += red[2][w];
            px  += red[3][w]; nx += red[4][w];
        }
        float contrib = 0.0f;
        if (active) {
            float Pf = (float)P, Nf = (float)N;
            float denom = Pf * Nf + 1e-8f;
            contrib = 1.0f
                    - apS / (Pf + 1e-8f)
                    + (t1 - t2) / denom
                    - (Nf * px - Pf * nx) / denom;
        }
        atomicAdd(out, contrib * (1.0f / (float)Cn));
    }
}

extern "C" void kernel_launch(void* const* d_in, const int* in_sizes, int n_in,
                              void* d_out, int out_size, void* d_ws, size_t ws_size,
                              hipStream_t stream) {
    const float* x   = (const float*)d_in[0];
    const int*   tgt = (const int*)d_in[1];
    const void*  msk = d_in[2];
    float* out = (float*)d_out;
    unsigned long long* keysT = (unsigned long long*)d_ws;   // 128*1024*8 = 1 MB

    hipMemsetAsync(out, 0, sizeof(float), stream);   // zero the loss accumulator
    hipLaunchKernelGGL(build_keys_kernel, dim3(128), dim3(256), 0, stream,
                       x, tgt, msk, keysT);
    hipLaunchKernelGGL(map_loss_kernel, dim3(Cn), dim3(TPB), 0, stream,
                       keysT, out);
}

// Round 11
// 72.522 us; speedup vs baseline: 1.0551x; 1.0551x over previous
//
#include <hip/hip_runtime.h>

// StructuredMAPLoss: B=1024 rows, C=128 classes.
// out[0] = loss (mean over classes), out[1 + i*C + c] = ranking[i][c].
// One block (512 threads, 2 elements/thread) per class.
// 32-bit sort keys: key = (kw & ~3) | f, invalid -> 0xFFFFFFFC (sorts last).
// Bitonic sort: j==1 in-reg, j=2..64 shfl_xor, j>=128 double-buffered LDS.
// r-histogram (2048 bins) for the pairwise score terms.

constexpr int Bn = 1024;
constexpr int Cn = 128;
constexpr int TPB = 512;
constexpr int E = 2;
constexpr int NBINS = 2048;
constexpr int ROFF = 3072;   // bin = (r + ROFF) >> 1 ; valid r in [-3071, 1023]

__device__ __forceinline__ unsigned long long pk3(int ff) {
    return (ff != 0 ? 1ull : 0ull) + (ff == 2 ? (1ull << 21) : 0ull) + (ff == 1 ? (1ull << 42) : 0ull);
}

__global__ __launch_bounds__(TPB) void map_loss_kernel(
    const float* __restrict__ x,
    const int* __restrict__ tgt,
    const void* __restrict__ maskraw,
    float* __restrict__ out)
{
    __shared__ unsigned int kbuf[2][Bn];             // 8 KB (double buffer)
    __shared__ unsigned int hist[NBINS];             // 8 KB
    __shared__ unsigned long long wtot[8];
    __shared__ unsigned int hwt[8];
    __shared__ int iwt[8];
    __shared__ float red[5][8];

    const int c    = blockIdx.x;
    const int tid  = threadIdx.x;
    const int lane = tid & 63;
    const int wid  = tid >> 6;

    // ---- mask storage sniff (redundant per-thread; wave-uniform, no barrier) ----
    int mode;
    {
        const int*   wi = (const int*)maskraw;
        const float* wf = (const float*)maskraw;
        bool okInt = true, okF = true;
        #pragma unroll 4
        for (int k = 0; k < 32; ++k) {
            int v = wi[k];
            if (v != 0 && v != 1) okInt = false;
            float fv = wf[k];
            if (fv != 0.0f && fv != 1.0f) okF = false;
        }
        mode = okInt ? 0 : (okF ? 1 : 2);
    }

    // ---- load 2 elements / thread; classify; zero histogram ----
    float xv[E]; int f[E];
    #pragma unroll
    for (int e = 0; e < E; ++e) {
        const int i = tid * E + e;
        const int g = i * Cn + c;
        xv[e] = x[g];
        int t = tgt[g];
        bool m;
        if (mode == 0)      m = ((const int*)maskraw)[g] != 0;
        else if (mode == 1) m = ((const float*)maskraw)[g] != 0.0f;
        else                m = ((const unsigned char*)maskraw)[g] != 0;
        f[e] = m ? ((t == 1) ? 1 : ((t == 0) ? 2 : 3)) : 0;
    }
    #pragma unroll
    for (int q = 0; q < NBINS / TPB; ++q) hist[tid * (NBINS / TPB) + q] = 0u;

    // ---- packed (valid,neg,pos) prefix scan over element order ----
    unsigned long long local = pk3(f[0]) + pk3(f[1]);
    unsigned long long v = local;
    #pragma unroll
    for (int off = 1; off < 64; off <<= 1) {
        unsigned long long o = __shfl_up(v, off);
        if (lane >= off) v += o;
    }
    if (lane == 63) wtot[wid] = v;
    __syncthreads();                                 // fences wtot + hist zero
    unsigned long long wpre = 0, tot = 0;
    #pragma unroll
    for (int w = 0; w < 8; ++w) {
        unsigned long long t = wtot[w];
        if (w < wid) wpre += t;
        tot += t;
    }
    unsigned long long run = wpre + v - local;       // exclusive prefix at i = tid*E

    const int M = (int)(tot & 0x1FFFFF);
    const int N = (int)((tot >> 21) & 0x1FFFFF);
    const int P = (int)((tot >> 42) & 0x1FFFFF);
    const bool active = (P > 0) && (N > 0);

    // ---- r closed form, ranking write, histogram atomics, 32-bit keys ----
    int r[E];
    unsigned int kr[E];
    #pragma unroll
    for (int e = 0; e < E; ++e) {
        const int i = tid * E + e;
        const int vb = (int)(run & 0x1FFFFF);
        const int nb = (int)((run >> 21) & 0x1FFFFF);
        const int pb = (int)((run >> 42) & 0x1FFFFF);
        const int mfi = (f[e] != 0) ? 1 : 0;
        const int bse = M - mfi - 2 * vb;
        r[e] = (f[e] == 1) ? bse + 2 * nb
             : ((f[e] == 2) ? bse + 2 * pb - 2 * P : bse);
        run += pk3(f[e]);

        out[1 + i * Cn + c] = (active && f[e] != 0) ? (float)r[e] : 0.0f;

        if (f[e] == 1)      atomicAdd(&hist[(r[e] + ROFF) >> 1], 1u << 16);
        else if (f[e] == 2) atomicAdd(&hist[(r[e] + ROFF) >> 1], 1u);

        unsigned int bits = __float_as_uint(xv[e]);
        unsigned int masc = bits ^ ((bits >> 31) ? 0xFFFFFFFFu : 0x80000000u);
        unsigned int kw = ~masc;                     // descending-x sorts first
        kr[e] = (f[e] == 0) ? 0xFFFFFFFCu
                            : ((kw & 0xFFFFFFFCu) | (unsigned int)f[e]);
    }

    // ---- bitonic sort (ascending): j==1 in-reg, j=2..64 shfl, j>=128 LDS ----
    int lb = 0;
    #pragma unroll
    for (int k = 2; k <= Bn; k <<= 1) {
        #pragma unroll
        for (int j = k >> 1; j > 0; j >>= 1) {
            if (j >= 128) {
                *(unsigned long long*)&kbuf[lb][tid * E] =
                    (unsigned long long)kr[0] | ((unsigned long long)kr[1] << 32);
                __syncthreads();                     // 6 of these total
                const int ptid = tid ^ (j >> 1);
                unsigned long long oo = *(const unsigned long long*)&kbuf[lb][ptid * E];
                unsigned int o0 = (unsigned int)oo;
                unsigned int o1 = (unsigned int)(oo >> 32);
                {
                    const int i = tid * E;
                    bool keepmin = ((i & k) == 0) == ((i & j) == 0);
                    kr[0] = ((kr[0] < o0) == keepmin) ? kr[0] : o0;
                    kr[1] = ((kr[1] < o1) == keepmin) ? kr[1] : o1;
                }
                lb ^= 1;                             // WAR safe: next write >=1 barrier away
            } else if (j >= E) {
                const int jl = j >> 1;               // lane distance 1..32
                #pragma unroll
                for (int e = 0; e < E; ++e) {
                    unsigned int o = __shfl_xor(kr[e], jl);
                    const int i = tid * E + e;
                    bool keepmin = ((i & k) == 0) == ((i & j) == 0);
                    kr[e] = ((kr[e] < o) == keepmin) ? kr[e] : o;
                }
            } else {                                 // j == 1: within thread
                const int i0 = tid * E;
                bool up = ((i0 & k) == 0);
                unsigned int a = kr[0], b = kr[1];
                bool sw = ((a > b) == up);
                kr[0] = sw ? b : a;
                kr[1] = sw ? a : b;
            }
        }
    }
    // kr[e] = key at sorted position i = tid*E+e (valids desc-x first, invalids last)

    // ---- histogram inclusive scan (4 bins/thread) + AP pos-indicator scan ----
    unsigned int h[NBINS / TPB]; unsigned int hl = 0;
    #pragma unroll
    for (int q = 0; q < NBINS / TPB; ++q) { h[q] = hist[tid * (NBINS / TPB) + q]; hl += h[q]; }
    unsigned int hv = hl;
    #pragma unroll
    for (int off = 1; off < 64; off <<= 1) {
        unsigned int o = __shfl_up(hv, off);
        if (lane >= off) hv += o;
    }
    if (lane == 63) hwt[wid] = hv;

    int ps[E]; int pl = 0;
    #pragma unroll
    for (int e = 0; e < E; ++e) { ps[e] = ((kr[e] & 3u) == 1u) ? 1 : 0; pl += ps[e]; }
    int pv = pl;
    #pragma unroll
    for (int off = 1; off < 64; off <<= 1) {
        int o = __shfl_up(pv, off);
        if (lane >= off) pv += o;
    }
    if (lane == 63) iwt[wid] = pv;
    __syncthreads();                                 // hwt + iwt ready

    unsigned int hpre = 0; int ppre = 0;
    #pragma unroll
    for (int w = 0; w < 8; ++w) {
        if (w < wid) { hpre += hwt[w]; ppre += iwt[w]; }
    }
    unsigned int hrun = hpre + hv - hl;
    #pragma unroll
    for (int q = 0; q < NBINS / TPB; ++q) { hrun += h[q]; hist[tid * (NBINS / TPB) + q] = hrun; }

    float S_ap = 0.0f;
    int prun = ppre + pv - pl;
    #pragma unroll
    for (int e = 0; e < E; ++e) {
        prun += ps[e];
        if (ps[e]) S_ap += (float)prun / (float)(tid * E + e + 1);
    }
    __syncthreads();                                 // inclusive hist visible

    // ---- per-element pairwise terms via histogram lookup ----
    float S_t1 = 0.0f, S_t2 = 0.0f, S_px = 0.0f, S_nx = 0.0f;
    #pragma unroll
    for (int e = 0; e < E; ++e) {
        if (f[e] == 1) {
            int rb = (r[e] + ROFF) >> 1;             // >= 1024, rb-1 safe
            int cnt = (int)(hist[rb - 1] & 0xFFFFu); // negs with r' < r
            S_t1 += xv[e] * (2.0f * (float)cnt - (float)N);
            S_px += xv[e];
        } else if (f[e] == 2) {
            int rb = (r[e] + ROFF) >> 1;
            int cnt = P - (int)(hist[rb] >> 16);     // pos with r' > r
            S_t2 += xv[e] * (2.0f * (float)cnt - (float)P);
            S_nx += xv[e];
        }
    }

    // ---- block reduction of 5 partial sums ----
    #pragma unroll
    for (int off = 32; off > 0; off >>= 1) {
        S_ap += __shfl_down(S_ap, off);
        S_t1 += __shfl_down(S_t1, off);
        S_t2 += __shfl_down(S_t2, off);
        S_px += __shfl_down(S_px, off);
        S_nx += __shfl_down(S_nx, off);
    }
    if (lane == 0) {
        red[0][wid] = S_ap; red[1][wid] = S_t1; red[2][wid] = S_t2;
        red[3][wid] = S_px; red[4][wid] = S_nx;
    }
    __syncthreads();
    if (tid == 0) {
        float apS = 0.f, t1 = 0.f, t2 = 0.f, px = 0.f, nx = 0.f;
        #pragma unroll
        for (int w = 0; w < 8; ++w) {
            apS += red[0][w]; t1 += red[1][w]; t2 += red[2][w];
            px  += red[3][w]; nx += red[4][w];
        }
        float contrib = 0.0f;
        if (active) {
            float Pf = (float)P, Nf = (float)N;
            float denom = Pf * Nf + 1e-8f;
            contrib = 1.0f
                    - apS / (Pf + 1e-8f)
                    + (t1 - t2) / denom
                    - (Nf * px - Pf * nx) / denom;
        }
        atomicAdd(out, contrib * (1.0f / (float)Cn));
    }
}

extern "C" void kernel_launch(void* const* d_in, const int* in_sizes, int n_in,
                              void* d_out, int out_size, void* d_ws, size_t ws_size,
                              hipStream_t stream) {
    const float* x   = (const float*)d_in[0];
    const int*   tgt = (const int*)d_in[1];
    const void*  msk = d_in[2];
    float* out = (float*)d_out;

    hipMemsetAsync(out, 0, sizeof(float), stream);   // zero the loss accumulator
    hipLaunchKernelGGL(map_loss_kernel, dim3(Cn), dim3(TPB), 0, stream,
                       x, tgt, msk, out);
}